// Round 1
// baseline (1833.630 us; speedup 1.0000x reference)
//
#include <hip/hip_runtime.h>
#include <math.h>

#define B_ 8
#define N_ 2048
#define D_ 256
#define K_ 8
#define NP_ 1024
#define H_ 128
#define EPS_ 1e-8f
#define NEG_INF_ (-1e30f)

__device__ __forceinline__ float gelu_exact(float x) {
    return 0.5f * x * (1.0f + erff(x * 0.70710678118654752440f));
}

__device__ __forceinline__ float dot4(float4 a, float4 b) {
    return a.x * b.x + a.y * b.y + a.z * b.z + a.w * b.w;
}

// block-wide (256 threads) sum reduction; returns total to all threads
__device__ __forceinline__ float bsum256(float* red, int t, float v) {
    red[t] = v;
    __syncthreads();
#pragma unroll
    for (int s = 128; s > 0; s >>= 1) {
        if (t < s) red[t] += red[t + s];
        __syncthreads();
    }
    float r = red[0];
    __syncthreads();
    return r;
}

__device__ __forceinline__ float bmax256(float* red, int t, float v) {
    red[t] = v;
    __syncthreads();
#pragma unroll
    for (int s = 128; s > 0; s >>= 1) {
        if (t < s) red[t] = fmaxf(red[t], red[t + s]);
        __syncthreads();
    }
    float r = red[0];
    __syncthreads();
    return r;
}

// ---------------- normalize tokens ----------------
__global__ __launch_bounds__(256) void k_norm(const float* __restrict__ tokens,
                                              float* __restrict__ tn) {
    int row = blockIdx.x;  // b*N + i
    int t = threadIdx.x;   // 256 = D
    __shared__ float red[256];
    float x = tokens[(size_t)row * D_ + t];
    float ss = bsum256(red, t, x * x);
    float nrm = sqrtf(ss) + EPS_;
    tn[(size_t)row * D_ + t] = x / nrm;
}

// ---------------- cosine-sim top-K (4 rows per block) ----------------
__global__ __launch_bounds__(256) void k_topk(const float* __restrict__ tn,
                                              int* __restrict__ topk) {
    int b = blockIdx.x >> 9;            // 512 blocks per batch
    int i0 = (blockIdx.x & 511) << 2;   // 4 rows
    const float* base = tn + (size_t)b * N_ * D_;
    __shared__ __align__(16) float tni[4][D_];
    __shared__ float sc[4][N_];
    __shared__ float rv[256];
    __shared__ int ri[256];
    int t = threadIdx.x;
    for (int e = t; e < 4 * D_; e += 256)
        tni[e >> 8][e & (D_ - 1)] = base[(size_t)(i0 + (e >> 8)) * D_ + (e & (D_ - 1))];
    __syncthreads();
    for (int pass = 0; pass < 4; ++pass) {
        int j0 = pass * 512 + t * 2;  // two consecutive j rows per thread
        const float* r0 = base + (size_t)j0 * D_;
        float a00 = 0, a01 = 0, a10 = 0, a11 = 0, a20 = 0, a21 = 0, a30 = 0, a31 = 0;
#pragma unroll 4
        for (int d = 0; d < D_; d += 4) {
            float4 u = *(const float4*)(r0 + d);
            float4 v = *(const float4*)(r0 + D_ + d);
            float4 w0 = *(const float4*)(&tni[0][d]);
            float4 w1 = *(const float4*)(&tni[1][d]);
            float4 w2 = *(const float4*)(&tni[2][d]);
            float4 w3 = *(const float4*)(&tni[3][d]);
            a00 += dot4(u, w0); a01 += dot4(v, w0);
            a10 += dot4(u, w1); a11 += dot4(v, w1);
            a20 += dot4(u, w2); a21 += dot4(v, w2);
            a30 += dot4(u, w3); a31 += dot4(v, w3);
        }
        sc[0][j0] = (j0 == i0 + 0) ? NEG_INF_ : a00;
        sc[0][j0 + 1] = (j0 + 1 == i0 + 0) ? NEG_INF_ : a01;
        sc[1][j0] = (j0 == i0 + 1) ? NEG_INF_ : a10;
        sc[1][j0 + 1] = (j0 + 1 == i0 + 1) ? NEG_INF_ : a11;
        sc[2][j0] = (j0 == i0 + 2) ? NEG_INF_ : a20;
        sc[2][j0 + 1] = (j0 + 1 == i0 + 2) ? NEG_INF_ : a21;
        sc[3][j0] = (j0 == i0 + 3) ? NEG_INF_ : a30;
        sc[3][j0 + 1] = (j0 + 1 == i0 + 3) ? NEG_INF_ : a31;
    }
    __syncthreads();
    for (int r = 0; r < 4; ++r) {
        for (int round = 0; round < K_; ++round) {
            float bv = NEG_INF_;
            int bj = N_;  // sentinel
#pragma unroll
            for (int s = 0; s < N_ / 256; ++s) {
                int j = s * 256 + t;
                float v = sc[r][j];
                if (v > bv || (v == bv && j < bj)) { bv = v; bj = j; }
            }
            rv[t] = bv; ri[t] = bj;
            __syncthreads();
#pragma unroll
            for (int s = 128; s > 0; s >>= 1) {
                if (t < s) {
                    float v2 = rv[t + s]; int j2 = ri[t + s];
                    if (v2 > rv[t] || (v2 == rv[t] && j2 < ri[t])) { rv[t] = v2; ri[t] = j2; }
                }
                __syncthreads();
            }
            if (t == 0) {
                topk[((size_t)(b * N_ + i0 + r)) * K_ + round] = ri[0];
                sc[r][ri[0]] = NEG_INF_;
            }
            __syncthreads();
        }
    }
}

// ---------------- mutual adjacency + degree-normalized aggregation ----------------
__global__ __launch_bounds__(64) void k_adj_agg(const float* __restrict__ tokens,
                                                const int* __restrict__ topk,
                                                int* __restrict__ nbr,
                                                int* __restrict__ deg,
                                                float* __restrict__ agg) {
    int row = blockIdx.x;  // b*N + i
    int b = row >> 11;
    int i = row & (N_ - 1);
    int t = threadIdx.x;
    __shared__ int s_cand[K_];
    __shared__ int s_nbr[K_];
    __shared__ int s_deg;
    if (t < K_) {
        int j = topk[(size_t)row * K_ + t];
        const int* tj = topk + ((size_t)(b * N_ + j)) * K_;
        bool mut = false;
#pragma unroll
        for (int k = 0; k < K_; ++k) mut = mut || (tj[k] == i);
        s_cand[t] = mut ? j : -1;
    }
    __syncthreads();
    if (t == 0) {  // deterministic in-order compaction
        int d = 0;
#pragma unroll
        for (int k = 0; k < K_; ++k)
            if (s_cand[k] >= 0) s_nbr[d++] = s_cand[k];
        s_deg = d;
    }
    __syncthreads();
    int dgi = s_deg;
    const float* tb = tokens + (size_t)b * N_ * D_;
    float a0 = 0, a1 = 0, a2 = 0, a3 = 0;
    for (int k = 0; k < dgi; ++k) {
        float4 v = *(const float4*)(tb + (size_t)s_nbr[k] * D_ + t * 4);
        a0 += v.x; a1 += v.y; a2 += v.z; a3 += v.w;
    }
    float inv = 1.0f / (float)(dgi > 0 ? dgi : 1);
    *(float4*)(agg + (size_t)row * D_ + t * 4) = make_float4(a0 * inv, a1 * inv, a2 * inv, a3 * inv);
    if (t < K_) nbr[(size_t)row * K_ + t] = (t < dgi) ? s_nbr[t] : -1;
    if (t == 0) deg[row] = dgi;
}

// ---------------- MLP layer 1 + exact GELU (4 rows per block) ----------------
__global__ __launch_bounds__(128) void k_mlp1(const float* __restrict__ tokens,
                                              const float* __restrict__ agg,
                                              const float* __restrict__ W1,
                                              const float* __restrict__ b1,
                                              float* __restrict__ h) {
    int row0 = blockIdx.x * 4;
    int t = threadIdx.x;  // 128 = H
    __shared__ float feat[4][2 * D_];
#pragma unroll
    for (int r = 0; r < 4; ++r)
        for (int c = t; c < D_; c += 128) {
            feat[r][c] = tokens[(size_t)(row0 + r) * D_ + c];
            feat[r][D_ + c] = agg[(size_t)(row0 + r) * D_ + c];
        }
    __syncthreads();
    float bias = b1[t];
    float acc0 = bias, acc1 = bias, acc2 = bias, acc3 = bias;
    for (int i = 0; i < 2 * D_; ++i) {
        float w = W1[(size_t)i * H_ + t];
        acc0 += feat[0][i] * w;
        acc1 += feat[1][i] * w;
        acc2 += feat[2][i] * w;
        acc3 += feat[3][i] * w;
    }
    h[(size_t)(row0 + 0) * H_ + t] = gelu_exact(acc0);
    h[(size_t)(row0 + 1) * H_ + t] = gelu_exact(acc1);
    h[(size_t)(row0 + 2) * H_ + t] = gelu_exact(acc2);
    h[(size_t)(row0 + 3) * H_ + t] = gelu_exact(acc3);
}

// ---------------- MLP layer 2 + softmax + entropy partials (4 rows per block) ----------------
__global__ __launch_bounds__(256) void k_mlp2(const float* __restrict__ hmat,
                                              const float* __restrict__ W2,
                                              const float* __restrict__ b2,
                                              float* __restrict__ assign,
                                              float* __restrict__ ent_partial) {
    int row0 = blockIdx.x * 4;
    int t = threadIdx.x;
    __shared__ float hs[4][H_];
    __shared__ float red[256];
    for (int e = t; e < 4 * H_; e += 256) hs[e >> 7][e & (H_ - 1)] = hmat[(size_t)row0 * H_ + e];
    __syncthreads();
    float acc[4][4];
#pragma unroll
    for (int s = 0; s < 4; ++s) {
        float bb = b2[s * 256 + t];
        acc[0][s] = bb; acc[1][s] = bb; acc[2][s] = bb; acc[3][s] = bb;
    }
    for (int i = 0; i < H_; ++i) {
        float w0 = W2[(size_t)i * NP_ + t];
        float w1 = W2[(size_t)i * NP_ + 256 + t];
        float w2 = W2[(size_t)i * NP_ + 512 + t];
        float w3 = W2[(size_t)i * NP_ + 768 + t];
#pragma unroll
        for (int r = 0; r < 4; ++r) {
            float hv = hs[r][i];
            acc[r][0] += hv * w0; acc[r][1] += hv * w1;
            acc[r][2] += hv * w2; acc[r][3] += hv * w3;
        }
    }
    float entv = 0.f;
    for (int r = 0; r < 4; ++r) {
        float m = bmax256(red, t, fmaxf(fmaxf(acc[r][0], acc[r][1]), fmaxf(acc[r][2], acc[r][3])));
        float e0 = expf(acc[r][0] - m), e1 = expf(acc[r][1] - m);
        float e2 = expf(acc[r][2] - m), e3 = expf(acc[r][3] - m);
        float tot = bsum256(red, t, e0 + e1 + e2 + e3);
        float inv = 1.0f / tot;
        float a0 = e0 * inv, a1 = e1 * inv, a2 = e2 * inv, a3 = e3 * inv;
        float* arow = assign + (size_t)(row0 + r) * NP_;
        arow[t] = a0; arow[256 + t] = a1; arow[512 + t] = a2; arow[768 + t] = a3;
        entv -= a0 * logf(a0 + EPS_) + a1 * logf(a1 + EPS_) + a2 * logf(a2 + EPS_) + a3 * logf(a3 + EPS_);
    }
    float bsum = bsum256(red, t, entv);
    if (t == 0) ent_partial[blockIdx.x] = bsum;
}

// ---------------- pooled_tokens = assign^T @ tokens (64x64 tile GEMM) ----------------
__global__ __launch_bounds__(256) void k_pool(const float* __restrict__ assign,
                                              const float* __restrict__ tokens,
                                              float* __restrict__ pooled) {
    int b = blockIdx.z;
    int p0 = blockIdx.y * 64;
    int d0 = blockIdx.x * 64;
    const float* A = assign + (size_t)b * N_ * NP_;
    const float* T = tokens + (size_t)b * N_ * D_;
    __shared__ __align__(16) float As[16][64];
    __shared__ __align__(16) float Ts[16][64];
    int tid = threadIdx.x;
    int tp = tid >> 4, td = tid & 15;
    float acc[4][4] = {};
    for (int n0 = 0; n0 < N_; n0 += 16) {
#pragma unroll
        for (int q = 0; q < 4; ++q) {
            int e = q * 256 + tid;
            int rr = e >> 6, cc = e & 63;
            As[rr][cc] = A[(size_t)(n0 + rr) * NP_ + p0 + cc];
            Ts[rr][cc] = T[(size_t)(n0 + rr) * D_ + d0 + cc];
        }
        __syncthreads();
#pragma unroll
        for (int kk = 0; kk < 16; ++kk) {
            float4 av = *(const float4*)(&As[kk][tp * 4]);
            float4 bv = *(const float4*)(&Ts[kk][td * 4]);
            float aa[4] = {av.x, av.y, av.z, av.w};
            float bb[4] = {bv.x, bv.y, bv.z, bv.w};
#pragma unroll
            for (int x = 0; x < 4; ++x)
#pragma unroll
                for (int y = 0; y < 4; ++y) acc[x][y] += aa[x] * bb[y];
        }
        __syncthreads();
    }
#pragma unroll
    for (int x = 0; x < 4; ++x) {
        float4 o = make_float4(acc[x][0], acc[x][1], acc[x][2], acc[x][3]);
        *(float4*)(pooled + ((size_t)b * NP_ + p0 + tp * 4 + x) * D_ + d0 + td * 4) = o;
    }
}

// ---------------- pooled timestamps ----------------
__global__ __launch_bounds__(256) void k_poolt(const float* __restrict__ assign,
                                               const float* __restrict__ ts,
                                               float* __restrict__ pooled_t_u) {
    int b = blockIdx.y;
    int p = blockIdx.x * 256 + threadIdx.x;
    const float* A = assign + (size_t)b * N_ * NP_ + p;
    const float* T = ts + (size_t)b * N_;
    float acc = 0.f;
    for (int n = 0; n < N_; ++n) acc += A[(size_t)n * NP_] * T[n];
    pooled_t_u[(size_t)b * NP_ + p] = acc;
}

// ---------------- ||A^T A||_F^2 partials (symmetric-half tiles) ----------------
__global__ __launch_bounds__(256) void k_gram(const float* __restrict__ assign,
                                              float* __restrict__ gram_partial) {
    int b = blockIdx.y;
    int idx = blockIdx.x;  // 0..135 triangular tile index over 16x16 tiles
    int a = 0, rem = idx;
    while (rem >= (NP_ / 64) - a) { rem -= (NP_ / 64) - a; ++a; }
    int bq = a + rem;
    int p0 = a * 64, q0 = bq * 64;
    const float* A = assign + (size_t)b * N_ * NP_;
    __shared__ __align__(16) float Ps[16][64];
    __shared__ __align__(16) float Qs[16][64];
    __shared__ float red[256];
    int tid = threadIdx.x;
    int tp = tid >> 4, td = tid & 15;
    float acc[4][4] = {};
    for (int n0 = 0; n0 < N_; n0 += 16) {
#pragma unroll
        for (int q = 0; q < 4; ++q) {
            int e = q * 256 + tid;
            int rr = e >> 6, cc = e & 63;
            Ps[rr][cc] = A[(size_t)(n0 + rr) * NP_ + p0 + cc];
            Qs[rr][cc] = A[(size_t)(n0 + rr) * NP_ + q0 + cc];
        }
        __syncthreads();
#pragma unroll
        for (int kk = 0; kk < 16; ++kk) {
            float4 av = *(const float4*)(&Ps[kk][tp * 4]);
            float4 bv = *(const float4*)(&Qs[kk][td * 4]);
            float aa[4] = {av.x, av.y, av.z, av.w};
            float bb[4] = {bv.x, bv.y, bv.z, bv.w};
#pragma unroll
            for (int x = 0; x < 4; ++x)
#pragma unroll
                for (int y = 0; y < 4; ++y) acc[x][y] += aa[x] * bb[y];
        }
        __syncthreads();
    }
    float lsum = 0.f;
#pragma unroll
    for (int x = 0; x < 4; ++x)
#pragma unroll
        for (int y = 0; y < 4; ++y) lsum += acc[x][y] * acc[x][y];
    float bsum = bsum256(red, tid, lsum);
    if (tid == 0) gram_partial[(size_t)b * 136 + idx] = (p0 == q0 ? 1.0f : 2.0f) * bsum;
}

// ---------------- sparse edge term: sum over edges of <a_i, a_j> ----------------
__global__ __launch_bounds__(64) void k_edge(const float* __restrict__ assign,
                                             const int* __restrict__ nbr,
                                             const int* __restrict__ deg,
                                             float* __restrict__ edge_partial) {
    int row = blockIdx.x;
    int t = threadIdx.x;
    int dgi = deg[row];
    int b = row >> 11;
    float acc = 0.f;
    if (dgi > 0) {
        const float* ai = assign + (size_t)row * NP_;
        float areg[16];
#pragma unroll
        for (int q = 0; q < 16; ++q) areg[q] = ai[q * 64 + t];
        for (int k = 0; k < dgi; ++k) {
            int j = nbr[(size_t)row * K_ + k];
            const float* aj = assign + ((size_t)(b * N_ + j)) * NP_;
#pragma unroll
            for (int q = 0; q < 16; ++q) acc += areg[q] * aj[q * 64 + t];
        }
    }
#pragma unroll
    for (int s = 32; s > 0; s >>= 1) acc += __shfl_down(acc, s);
    if (t == 0) edge_partial[row] = acc;
}

// ---------------- per-batch bitonic sort of (pooled_t, idx) ----------------
__global__ __launch_bounds__(256) void k_sort(const float* __restrict__ pooled_t_u,
                                              float* __restrict__ out_pt,
                                              int* __restrict__ sortidx) {
    int b = blockIdx.x;
    int t = threadIdx.x;
    __shared__ float val[NP_];
    __shared__ int sidx[NP_];
    for (int e = t; e < NP_; e += 256) { val[e] = pooled_t_u[(size_t)b * NP_ + e]; sidx[e] = e; }
    __syncthreads();
    for (int k = 2; k <= NP_; k <<= 1) {
        for (int j = k >> 1; j > 0; j >>= 1) {
            for (int e = t; e < NP_; e += 256) {
                int l = e ^ j;
                if (l > e) {
                    bool up = ((e & k) == 0);
                    float v1 = val[e], v2 = val[l];
                    int i1 = sidx[e], i2 = sidx[l];
                    bool g = (v1 > v2) || (v1 == v2 && i1 > i2);
                    bool sw = up ? g : ((v1 < v2) || (v1 == v2 && i1 < i2));
                    if (sw) { val[e] = v2; val[l] = v1; sidx[e] = i2; sidx[l] = i1; }
                }
            }
            __syncthreads();
        }
    }
    for (int e = t; e < NP_; e += 256) {
        out_pt[(size_t)b * NP_ + e] = val[e];
        sortidx[(size_t)b * NP_ + e] = sidx[e];
    }
}

// ---------------- gather pooled token rows in sorted order ----------------
__global__ __launch_bounds__(64) void k_gather(const float* __restrict__ pooledU,
                                               const int* __restrict__ sortidx,
                                               float* __restrict__ out) {
    int bp = blockIdx.x;  // b*NP + sorted position
    int b = bp >> 10;
    int src = sortidx[bp];
    const float4* s = (const float4*)(pooledU + ((size_t)(b << 10) + src) * D_);
    float4* d = (float4*)(out + (size_t)bp * D_);
    d[threadIdx.x] = s[threadIdx.x];
}

// ---------------- deterministic final reduce: link_loss + entropy ----------------
__global__ __launch_bounds__(256) void k_fin(const float* __restrict__ gram_partial,
                                             const float* __restrict__ edge_partial,
                                             const float* __restrict__ ent_partial,
                                             const int* __restrict__ deg,
                                             float* __restrict__ out2) {
    int t = threadIdx.x;
    __shared__ float red[256];
    float t1 = 0.f, t2 = 0.f, t3 = 0.f, ent = 0.f;
    for (int i = t; i < 136 * B_; i += 256) t1 += gram_partial[i];
    for (int i = t; i < B_ * N_; i += 256) t2 += edge_partial[i];
    for (int i = t; i < (B_ * N_) / 4; i += 256) ent += ent_partial[i];
    for (int i = t; i < B_ * N_; i += 256) t3 += (float)deg[i];
    t1 = bsum256(red, t, t1);
    t2 = bsum256(red, t, t2);
    t3 = bsum256(red, t, t3);
    ent = bsum256(red, t, ent);
    if (t == 0) {
        out2[0] = (t1 - 2.f * t2 + t3) / (float)((size_t)B_ * N_ * N_);
        out2[1] = ent / (float)(B_ * N_);
    }
}

extern "C" void kernel_launch(void* const* d_in, const int* in_sizes, int n_in,
                              void* d_out, int out_size, void* d_ws, size_t ws_size,
                              hipStream_t stream) {
    const float* tokens = (const float*)d_in[0];
    const float* tstamp = (const float*)d_in[1];
    const float* W1 = (const float*)d_in[2];
    const float* b1 = (const float*)d_in[3];
    const float* W2 = (const float*)d_in[4];
    const float* b2 = (const float*)d_in[5];
    float* out = (float*)d_out;

    char* wsp = (char*)d_ws;
    size_t off = 0;
    auto alloc = [&](size_t bytes) -> void* {
        void* p = wsp + off;
        off += (bytes + 255) & ~(size_t)255;
        return p;
    };
    float* tn = (float*)alloc(sizeof(float) * (size_t)B_ * N_ * D_);       // 16.8 MB
    float* agg = tn;  // tn is dead after k_topk; reuse for agg
    float* hbuf = (float*)alloc(sizeof(float) * (size_t)B_ * N_ * H_);     // 8.4 MB
    float* assign = (float*)alloc(sizeof(float) * (size_t)B_ * N_ * NP_);  // 67.1 MB
    float* pooledU = (float*)alloc(sizeof(float) * (size_t)B_ * NP_ * D_); // 8.4 MB
    float* pooltU = (float*)alloc(sizeof(float) * (size_t)B_ * NP_);
    int* topkbuf = (int*)alloc(sizeof(int) * (size_t)B_ * N_ * K_);
    int* nbrbuf = (int*)alloc(sizeof(int) * (size_t)B_ * N_ * K_);
    int* degbuf = (int*)alloc(sizeof(int) * (size_t)B_ * N_);
    int* sortidx = (int*)alloc(sizeof(int) * (size_t)B_ * NP_);
    float* gram_p = (float*)alloc(sizeof(float) * 136 * B_);
    float* edge_p = (float*)alloc(sizeof(float) * (size_t)B_ * N_);
    float* ent_p = (float*)alloc(sizeof(float) * (size_t)(B_ * N_) / 4);

    k_norm<<<B_ * N_, 256, 0, stream>>>(tokens, tn);
    k_topk<<<(B_ * N_) / 4, 256, 0, stream>>>(tn, topkbuf);
    k_adj_agg<<<B_ * N_, 64, 0, stream>>>(tokens, topkbuf, nbrbuf, degbuf, agg);
    k_mlp1<<<(B_ * N_) / 4, 128, 0, stream>>>(tokens, agg, W1, b1, hbuf);
    k_mlp2<<<(B_ * N_) / 4, 256, 0, stream>>>(hbuf, W2, b2, assign, ent_p);
    k_pool<<<dim3(D_ / 64, NP_ / 64, B_), 256, 0, stream>>>(assign, tokens, pooledU);
    k_poolt<<<dim3(NP_ / 256, B_), 256, 0, stream>>>(assign, tstamp, pooltU);
    k_gram<<<dim3(136, B_), 256, 0, stream>>>(assign, gram_p);
    k_edge<<<B_ * N_, 64, 0, stream>>>(assign, nbrbuf, degbuf, edge_p);
    k_sort<<<B_, 256, 0, stream>>>(pooltU, out + (size_t)B_ * NP_ * D_, sortidx);
    k_gather<<<B_ * NP_, 64, 0, stream>>>(pooledU, sortidx, out);
    k_fin<<<1, 256, 0, stream>>>(gram_p, edge_p, ent_p, degbuf,
                                 out + (size_t)B_ * NP_ * D_ + (size_t)B_ * NP_);
}

// Round 2
// 838.174 us; speedup vs baseline: 2.1876x; 2.1876x over previous
//
#include <hip/hip_runtime.h>
#include <math.h>

#define B_ 8
#define N_ 2048
#define D_ 256
#define K_ 8
#define NP_ 1024
#define H_ 128
#define EPS_ 1e-8f
#define NEG_INF_ (-1e30f)

typedef unsigned int uint;
typedef unsigned short ushort;
typedef __attribute__((ext_vector_type(4))) float f32x4;
typedef __attribute__((ext_vector_type(8))) short short8;

__device__ __forceinline__ float gelu_exact(float x) {
    return 0.5f * x * (1.0f + erff(x * 0.70710678118654752440f));
}

__device__ __forceinline__ float dot4(float4 a, float4 b) {
    return a.x * b.x + a.y * b.y + a.z * b.z + a.w * b.w;
}

__device__ __forceinline__ ushort f2bf(float f) {
    uint u = __float_as_uint(f);
    u = (u + 0x7FFFu + ((u >> 16) & 1u)) >> 16;
    return (ushort)u;
}

__device__ __forceinline__ float bsum256(float* red, int t, float v) {
    red[t] = v;
    __syncthreads();
#pragma unroll
    for (int s = 128; s > 0; s >>= 1) {
        if (t < s) red[t] += red[t + s];
        __syncthreads();
    }
    float r = red[0];
    __syncthreads();
    return r;
}

__device__ __forceinline__ float bmax256(float* red, int t, float v) {
    red[t] = v;
    __syncthreads();
#pragma unroll
    for (int s = 128; s > 0; s >>= 1) {
        if (t < s) red[t] = fmaxf(red[t], red[t + s]);
        __syncthreads();
    }
    float r = red[0];
    __syncthreads();
    return r;
}

// ---------------- normalize tokens -> tn fp32 + tnbf bf16 ----------------
__global__ __launch_bounds__(256) void k_norm(const float* __restrict__ tokens,
                                              float* __restrict__ tn,
                                              ushort* __restrict__ tnbf) {
    int row = blockIdx.x;
    int t = threadIdx.x;
    __shared__ float red[256];
    float x = tokens[(size_t)row * D_ + t];
    float ss = bsum256(red, t, x * x);
    float nrm = sqrtf(ss) + EPS_;
    float y = x / nrm;
    tn[(size_t)row * D_ + t] = y;
    tnbf[(size_t)row * D_ + t] = f2bf(y);
}

// ================= shared MFMA XX^T-style tile core =================
// A: 128 rows (row stride K ushorts), B: 128 rows. Computes 128x128 fp32 acc.
// LDS layout per side: [row 128][8 slots of 16B], slot XOR-swizzled by (row&7).
__device__ __forceinline__ void gemm_xxt_tile(const ushort* __restrict__ A,
                                              const ushort* __restrict__ B,
                                              int K, f32x4 acc[4][4], char* lds) {
    int t = threadIdx.x;
    int lane = t & 63;
    int wid = t >> 6;
    int wm = wid >> 1, wn = wid & 1;
    for (int kb = 0; kb < K; kb += 64) {
        uint4 ra[4], rb[4];
#pragma unroll
        for (int c = 0; c < 4; ++c) {
            int s = c * 256 + t;
            int row = s >> 3, g = s & 7;
            ra[c] = *(const uint4*)(A + (size_t)row * K + kb + g * 8);
            rb[c] = *(const uint4*)(B + (size_t)row * K + kb + g * 8);
        }
        __syncthreads();
#pragma unroll
        for (int c = 0; c < 4; ++c) {
            int s = c * 256 + t;
            int row = s >> 3, g = s & 7;
            int off = row * 128 + ((g ^ (row & 7)) * 16);
            *(uint4*)(lds + off) = ra[c];
            *(uint4*)(lds + 16384 + off) = rb[c];
        }
        __syncthreads();
#pragma unroll
        for (int ks = 0; ks < 2; ++ks) {
            short8 afr[4], bfr[4];
#pragma unroll
            for (int f = 0; f < 4; ++f) {
                int rowA = wm * 64 + f * 16 + (lane & 15);
                int u = ks * 4 + (lane >> 4);
                afr[f] = *(const short8*)(lds + rowA * 128 + ((u ^ (rowA & 7)) * 16));
                int rowB = wn * 64 + f * 16 + (lane & 15);
                bfr[f] = *(const short8*)(lds + 16384 + rowB * 128 + ((u ^ (rowB & 7)) * 16));
            }
#pragma unroll
            for (int fm = 0; fm < 4; ++fm)
#pragma unroll
                for (int fn = 0; fn < 4; ++fn)
                    acc[fm][fn] = __builtin_amdgcn_mfma_f32_16x16x32_bf16(
                        afr[fm], bfr[fn], acc[fm][fn], 0, 0, 0);
        }
    }
}

// ---------------- S = tn tn^T (bf16 out) ----------------
__global__ __launch_bounds__(256) void k_simgemm(const ushort* __restrict__ tnbf,
                                                 ushort* __restrict__ S) {
    __shared__ __align__(16) char lds[32768];
    int b = blockIdx.z;
    int i0 = blockIdx.y * 128, j0 = blockIdx.x * 128;
    const ushort* A = tnbf + ((size_t)b * N_ + i0) * D_;
    const ushort* Bp = tnbf + ((size_t)b * N_ + j0) * D_;
    f32x4 acc[4][4];
#pragma unroll
    for (int x = 0; x < 4; ++x)
#pragma unroll
        for (int y = 0; y < 4; ++y) acc[x][y] = (f32x4){0.f, 0.f, 0.f, 0.f};
    gemm_xxt_tile(A, Bp, D_, acc, lds);
    int lane = threadIdx.x & 63;
    int wid = threadIdx.x >> 6;
    int wm = wid >> 1, wn = wid & 1;
    ushort* Sb = S + (size_t)b * N_ * N_;
#pragma unroll
    for (int fm = 0; fm < 4; ++fm)
#pragma unroll
        for (int fn = 0; fn < 4; ++fn) {
            int i = i0 + wm * 64 + fm * 16 + (lane >> 4) * 4;
            int j = j0 + wn * 64 + fn * 16 + (lane & 15);
#pragma unroll
            for (int v = 0; v < 4; ++v)
                Sb[(size_t)(i + v) * N_ + j] = f2bf(acc[fm][fn][v]);
        }
}

// ---------------- top-16 candidates from bf16 S (1 wave per row) ----------------
__device__ __forceinline__ uint mono16(uint v) {
    return (v & 0x8000u) ? ((~v) & 0xFFFFu) : (v | 0x8000u);
}

__global__ __launch_bounds__(256) void k_cand16(const ushort* __restrict__ S,
                                                int* __restrict__ cands) {
    int wid = threadIdx.x >> 6;
    int lane = threadIdx.x & 63;
    int row = blockIdx.x * 4 + wid;  // b*N + i
    int b = row >> 11, i = row & (N_ - 1);
    const ushort* srow = S + (size_t)b * N_ * N_ + (size_t)i * N_;
    uint l0 = 0, l1 = 0, l2 = 0, l3 = 0, l4 = 0, l5 = 0, l6 = 0, l7 = 0;
#define INS_(L) { bool ins_ = key > L; uint tmp_ = L; L = ins_ ? key : L; key = ins_ ? tmp_ : key; }
#pragma unroll
    for (int c = 0; c < 4; ++c) {
        int jb = c * 512 + lane * 8;
        uint4 q = *(const uint4*)(srow + jb);
        uint vv[8] = {q.x & 0xFFFFu, q.x >> 16, q.y & 0xFFFFu, q.y >> 16,
                      q.z & 0xFFFFu, q.z >> 16, q.w & 0xFFFFu, q.w >> 16};
#pragma unroll
        for (int e = 0; e < 8; ++e) {
            int j = jb + e;
            if (j == i) continue;
            uint key = (mono16(vv[e]) << 16) | (65535u - (uint)j);
            if (key > l7) { INS_(l0) INS_(l1) INS_(l2) INS_(l3) INS_(l4) INS_(l5) INS_(l6) INS_(l7) }
        }
    }
#undef INS_
    int myj = 0;
#pragma unroll
    for (int r = 0; r < 16; ++r) {
        uint cand = l0;
        uint m = cand;
#pragma unroll
        for (int s = 1; s < 64; s <<= 1) {
            uint o = (uint)__shfl_xor((int)m, s);
            m = m > o ? m : o;
        }
        unsigned long long mk = __ballot(cand == m);
        int wl = __ffsll(mk) - 1;
        if (lane == wl) { l0 = l1; l1 = l2; l2 = l3; l3 = l4; l4 = l5; l5 = l6; l6 = l7; l7 = 0; }
        if (lane == r) myj = (int)(65535u - (m & 0xFFFFu));
    }
    if (lane < 16) cands[(size_t)row * 16 + lane] = myj;
}

// ---------------- exact fp32 rescore of 16 candidates -> top-8 ----------------
__global__ __launch_bounds__(64) void k_rescore(const float* __restrict__ tn,
                                                const int* __restrict__ cands,
                                                int* __restrict__ topk) {
    int row = blockIdx.x;
    int b = row >> 11;
    int lane = threadIdx.x;
    int j = cands[(size_t)row * 16 + (lane & 15)];
    float s = 0.f;
    if (lane < 16) {
        const float* ti = tn + (size_t)row * D_;
        const float* tj = tn + ((size_t)(b << 11) + j) * D_;
        for (int d = 0; d < D_; d += 4) {
            float4 u = *(const float4*)(tj + d);
            float4 w = *(const float4*)(ti + d);
            s += dot4(u, w);
        }
    }
    float dv[16];
    int jv[16];
#pragma unroll
    for (int c = 0; c < 16; ++c) {
        dv[c] = __shfl(s, c);
        jv[c] = __shfl(j, c);
    }
    uint used = 0;
    for (int r = 0; r < 8; ++r) {
        float bv = -1e38f;
        int bj = 1 << 30, bc = -1;
#pragma unroll
        for (int c = 0; c < 16; ++c) {
            bool av = !(used & (1u << c));
            bool better = av && (dv[c] > bv || (dv[c] == bv && jv[c] < bj));
            bv = better ? dv[c] : bv;
            bj = better ? jv[c] : bj;
            bc = better ? c : bc;
        }
        used |= 1u << bc;
        if (lane == 0) topk[(size_t)row * K_ + r] = bj;
    }
}

// ---------------- mutual adjacency + degree-normalized aggregation ----------------
__global__ __launch_bounds__(64) void k_adj_agg(const float* __restrict__ tokens,
                                                const int* __restrict__ topk,
                                                int* __restrict__ nbr,
                                                int* __restrict__ deg,
                                                float* __restrict__ agg) {
    int row = blockIdx.x;
    int b = row >> 11;
    int i = row & (N_ - 1);
    int t = threadIdx.x;
    __shared__ int s_cand[K_];
    __shared__ int s_nbr[K_];
    __shared__ int s_deg;
    if (t < K_) {
        int j = topk[(size_t)row * K_ + t];
        const int* tj = topk + ((size_t)(b * N_ + j)) * K_;
        bool mut = false;
#pragma unroll
        for (int k = 0; k < K_; ++k) mut = mut || (tj[k] == i);
        s_cand[t] = mut ? j : -1;
    }
    __syncthreads();
    if (t == 0) {
        int d = 0;
#pragma unroll
        for (int k = 0; k < K_; ++k)
            if (s_cand[k] >= 0) s_nbr[d++] = s_cand[k];
        s_deg = d;
    }
    __syncthreads();
    int dgi = s_deg;
    const float* tb = tokens + (size_t)b * N_ * D_;
    float a0 = 0, a1 = 0, a2 = 0, a3 = 0;
    for (int k = 0; k < dgi; ++k) {
        float4 v = *(const float4*)(tb + (size_t)s_nbr[k] * D_ + t * 4);
        a0 += v.x; a1 += v.y; a2 += v.z; a3 += v.w;
    }
    float inv = 1.0f / (float)(dgi > 0 ? dgi : 1);
    *(float4*)(agg + (size_t)row * D_ + t * 4) = make_float4(a0 * inv, a1 * inv, a2 * inv, a3 * inv);
    if (t < K_) nbr[(size_t)row * K_ + t] = (t < dgi) ? s_nbr[t] : -1;
    if (t == 0) deg[row] = dgi;
}

// ---------------- transpose-cast: tokens [N][D] f32 -> tokT [D][N] bf16 ----------------
__global__ __launch_bounds__(256) void k_tokT(const float* __restrict__ tokens,
                                              ushort* __restrict__ tokT) {
    int b = blockIdx.z;
    int n0 = blockIdx.x * 32, d0 = blockIdx.y * 32;
    __shared__ float tile[32][33];
    int t = threadIdx.x;
#pragma unroll
    for (int q = 0; q < 4; ++q) {
        int e = q * 256 + t;
        int r = e >> 5, c = e & 31;
        tile[r][c] = tokens[((size_t)b * N_ + n0 + r) * D_ + d0 + c];
    }
    __syncthreads();
#pragma unroll
    for (int q = 0; q < 4; ++q) {
        int e = q * 256 + t;
        int r = e >> 5, c = e & 31;
        tokT[((size_t)b * D_ + d0 + r) * N_ + n0 + c] = f2bf(tile[c][r]);
    }
}

// ---------------- transpose-cast: assign [N][NP] f32 -> assignT [NP][N] bf16 ----------------
__global__ __launch_bounds__(256) void k_asT(const float* __restrict__ assign,
                                             ushort* __restrict__ assignT) {
    int b = blockIdx.z;
    int n0 = blockIdx.x * 32, p0 = blockIdx.y * 32;
    __shared__ float tile[32][33];
    int t = threadIdx.x;
#pragma unroll
    for (int q = 0; q < 4; ++q) {
        int e = q * 256 + t;
        int r = e >> 5, c = e & 31;
        tile[r][c] = assign[((size_t)b * N_ + n0 + r) * NP_ + p0 + c];
    }
    __syncthreads();
#pragma unroll
    for (int q = 0; q < 4; ++q) {
        int e = q * 256 + t;
        int r = e >> 5, c = e & 31;
        assignT[((size_t)b * NP_ + p0 + r) * N_ + n0 + c] = f2bf(tile[c][r]);
    }
}

// ---------------- MLP layer 1 + exact GELU (8 rows per block) ----------------
__global__ __launch_bounds__(128) void k_mlp1(const float* __restrict__ tokens,
                                              const float* __restrict__ agg,
                                              const float* __restrict__ W1,
                                              const float* __restrict__ b1,
                                              float* __restrict__ h) {
    int row0 = blockIdx.x * 8;
    int t = threadIdx.x;
    __shared__ float feat[8][2 * D_];
    for (int e = t; e < 8 * 2 * D_; e += 128) {
        int r = e >> 9, c = e & 511;
        feat[r][c] = (c < D_) ? tokens[(size_t)(row0 + r) * D_ + c]
                              : agg[(size_t)(row0 + r) * D_ + (c - D_)];
    }
    __syncthreads();
    float bias = b1[t];
    float a0 = bias, a1 = bias, a2 = bias, a3 = bias, a4 = bias, a5 = bias, a6 = bias, a7 = bias;
    for (int i = 0; i < 2 * D_; ++i) {
        float w = W1[(size_t)i * H_ + t];
        a0 += feat[0][i] * w; a1 += feat[1][i] * w;
        a2 += feat[2][i] * w; a3 += feat[3][i] * w;
        a4 += feat[4][i] * w; a5 += feat[5][i] * w;
        a6 += feat[6][i] * w; a7 += feat[7][i] * w;
    }
    h[(size_t)(row0 + 0) * H_ + t] = gelu_exact(a0);
    h[(size_t)(row0 + 1) * H_ + t] = gelu_exact(a1);
    h[(size_t)(row0 + 2) * H_ + t] = gelu_exact(a2);
    h[(size_t)(row0 + 3) * H_ + t] = gelu_exact(a3);
    h[(size_t)(row0 + 4) * H_ + t] = gelu_exact(a4);
    h[(size_t)(row0 + 5) * H_ + t] = gelu_exact(a5);
    h[(size_t)(row0 + 6) * H_ + t] = gelu_exact(a6);
    h[(size_t)(row0 + 7) * H_ + t] = gelu_exact(a7);
}

// ---------------- MLP layer 2 + softmax + entropy (8 rows per block) ----------------
__global__ __launch_bounds__(256) void k_mlp2(const float* __restrict__ hmat,
                                              const float* __restrict__ W2,
                                              const float* __restrict__ b2,
                                              float* __restrict__ assign,
                                              float* __restrict__ ent_partial) {
    int row0 = blockIdx.x * 8;
    int t = threadIdx.x;
    __shared__ float hs[8][H_];
    __shared__ float red[256];
    for (int e = t; e < 8 * H_; e += 256) hs[e >> 7][e & (H_ - 1)] = hmat[(size_t)row0 * H_ + e];
    __syncthreads();
    float acc[8][4];
#pragma unroll
    for (int s = 0; s < 4; ++s) {
        float bb = b2[s * 256 + t];
#pragma unroll
        for (int r = 0; r < 8; ++r) acc[r][s] = bb;
    }
    for (int i = 0; i < H_; ++i) {
        float w0 = W2[(size_t)i * NP_ + t];
        float w1 = W2[(size_t)i * NP_ + 256 + t];
        float w2 = W2[(size_t)i * NP_ + 512 + t];
        float w3 = W2[(size_t)i * NP_ + 768 + t];
#pragma unroll
        for (int r = 0; r < 8; ++r) {
            float hv = hs[r][i];
            acc[r][0] += hv * w0; acc[r][1] += hv * w1;
            acc[r][2] += hv * w2; acc[r][3] += hv * w3;
        }
    }
    float entv = 0.f;
#pragma unroll
    for (int r = 0; r < 8; ++r) {
        float m = bmax256(red, t, fmaxf(fmaxf(acc[r][0], acc[r][1]), fmaxf(acc[r][2], acc[r][3])));
        float e0 = expf(acc[r][0] - m), e1 = expf(acc[r][1] - m);
        float e2 = expf(acc[r][2] - m), e3 = expf(acc[r][3] - m);
        float tot = bsum256(red, t, e0 + e1 + e2 + e3);
        float inv = 1.0f / tot;
        float p0 = e0 * inv, p1 = e1 * inv, p2 = e2 * inv, p3 = e3 * inv;
        float* arow = assign + (size_t)(row0 + r) * NP_;
        arow[t] = p0; arow[256 + t] = p1; arow[512 + t] = p2; arow[768 + t] = p3;
        entv -= p0 * logf(p0 + EPS_) + p1 * logf(p1 + EPS_) + p2 * logf(p2 + EPS_) + p3 * logf(p3 + EPS_);
    }
    float bsum = bsum256(red, t, entv);
    if (t == 0) ent_partial[blockIdx.x] = bsum;
}

// ---------------- pooled = assignT . tokT^T via MFMA (fp32 out) ----------------
__global__ __launch_bounds__(256) void k_poolM(const ushort* __restrict__ assignT,
                                               const ushort* __restrict__ tokT,
                                               float* __restrict__ pooled) {
    __shared__ __align__(16) char lds[32768];
    int b = blockIdx.z;
    int pt = blockIdx.y, dt = blockIdx.x;
    const ushort* A = assignT + ((size_t)b * NP_ + pt * 128) * N_;
    const ushort* Bp = tokT + ((size_t)b * D_ + dt * 128) * N_;
    f32x4 acc[4][4];
#pragma unroll
    for (int x = 0; x < 4; ++x)
#pragma unroll
        for (int y = 0; y < 4; ++y) acc[x][y] = (f32x4){0.f, 0.f, 0.f, 0.f};
    gemm_xxt_tile(A, Bp, N_, acc, lds);
    int lane = threadIdx.x & 63;
    int wid = threadIdx.x >> 6;
    int wm = wid >> 1, wn = wid & 1;
#pragma unroll
    for (int fm = 0; fm < 4; ++fm)
#pragma unroll
        for (int fn = 0; fn < 4; ++fn) {
            int p = pt * 128 + wm * 64 + fm * 16 + (lane >> 4) * 4;
            int d = dt * 128 + wn * 64 + fn * 16 + (lane & 15);
#pragma unroll
            for (int v = 0; v < 4; ++v)
                pooled[((size_t)b * NP_ + p + v) * D_ + d] = acc[fm][fn][v];
        }
}

// ---------------- gram: sum of (A^T A)^2 via MFMA, triangular tiles ----------------
__global__ __launch_bounds__(256) void k_gramM(const ushort* __restrict__ assignT,
                                               float* __restrict__ gram_partial) {
    __shared__ __align__(16) char lds[32768];
    __shared__ float red[256];
    int b = blockIdx.y;
    int idx = blockIdx.x;  // 0..35 over 8x8 tiles, ti<=tj
    int ti = 0, rem = idx;
    while (rem >= 8 - ti) { rem -= 8 - ti; ++ti; }
    int tj = ti + rem;
    const ushort* A = assignT + ((size_t)b * NP_ + ti * 128) * N_;
    const ushort* Bp = assignT + ((size_t)b * NP_ + tj * 128) * N_;
    f32x4 acc[4][4];
#pragma unroll
    for (int x = 0; x < 4; ++x)
#pragma unroll
        for (int y = 0; y < 4; ++y) acc[x][y] = (f32x4){0.f, 0.f, 0.f, 0.f};
    gemm_xxt_tile(A, Bp, N_, acc, lds);
    float lsum = 0.f;
#pragma unroll
    for (int x = 0; x < 4; ++x)
#pragma unroll
        for (int y = 0; y < 4; ++y)
#pragma unroll
            for (int v = 0; v < 4; ++v) lsum += acc[x][y][v] * acc[x][y][v];
    float bs = bsum256(red, threadIdx.x, lsum);
    if (threadIdx.x == 0) gram_partial[(size_t)b * 36 + idx] = (ti == tj ? 1.0f : 2.0f) * bs;
}

// ---------------- pooled timestamps (exact fp32) ----------------
__global__ __launch_bounds__(256) void k_poolt(const float* __restrict__ assign,
                                               const float* __restrict__ ts,
                                               float* __restrict__ pooled_t_u) {
    int b = blockIdx.y;
    int p = blockIdx.x * 256 + threadIdx.x;
    const float* A = assign + (size_t)b * N_ * NP_ + p;
    const float* T = ts + (size_t)b * N_;
    float acc = 0.f;
    for (int n = 0; n < N_; ++n) acc += A[(size_t)n * NP_] * T[n];
    pooled_t_u[(size_t)b * NP_ + p] = acc;
}

// ---------------- sparse edge term ----------------
__global__ __launch_bounds__(64) void k_edge(const float* __restrict__ assign,
                                             const int* __restrict__ nbr,
                                             const int* __restrict__ deg,
                                             float* __restrict__ edge_partial) {
    int row = blockIdx.x;
    int t = threadIdx.x;
    int dgi = deg[row];
    int b = row >> 11;
    float acc = 0.f;
    if (dgi > 0) {
        const float* ai = assign + (size_t)row * NP_;
        float areg[16];
#pragma unroll
        for (int q = 0; q < 16; ++q) areg[q] = ai[q * 64 + t];
        for (int k = 0; k < dgi; ++k) {
            int j = nbr[(size_t)row * K_ + k];
            const float* aj = assign + ((size_t)(b * N_ + j)) * NP_;
#pragma unroll
            for (int q = 0; q < 16; ++q) acc += areg[q] * aj[q * 64 + t];
        }
    }
#pragma unroll
    for (int s = 32; s > 0; s >>= 1) acc += __shfl_down(acc, s);
    if (t == 0) edge_partial[row] = acc;
}

// ---------------- per-batch bitonic sort of (pooled_t, idx) ----------------
__global__ __launch_bounds__(256) void k_sort(const float* __restrict__ pooled_t_u,
                                              float* __restrict__ out_pt,
                                              int* __restrict__ sortidx) {
    int b = blockIdx.x;
    int t = threadIdx.x;
    __shared__ float val[NP_];
    __shared__ int sidx[NP_];
    for (int e = t; e < NP_; e += 256) { val[e] = pooled_t_u[(size_t)b * NP_ + e]; sidx[e] = e; }
    __syncthreads();
    for (int k = 2; k <= NP_; k <<= 1) {
        for (int j = k >> 1; j > 0; j >>= 1) {
            for (int e = t; e < NP_; e += 256) {
                int l = e ^ j;
                if (l > e) {
                    bool up = ((e & k) == 0);
                    float v1 = val[e], v2 = val[l];
                    int i1 = sidx[e], i2 = sidx[l];
                    bool sw = up ? ((v1 > v2) || (v1 == v2 && i1 > i2))
                                 : ((v1 < v2) || (v1 == v2 && i1 < i2));
                    if (sw) { val[e] = v2; val[l] = v1; sidx[e] = i2; sidx[l] = i1; }
                }
            }
            __syncthreads();
        }
    }
    for (int e = t; e < NP_; e += 256) {
        out_pt[(size_t)b * NP_ + e] = val[e];
        sortidx[(size_t)b * NP_ + e] = sidx[e];
    }
}

// ---------------- gather pooled rows in sorted order ----------------
__global__ __launch_bounds__(64) void k_gather(const float* __restrict__ pooledU,
                                               const int* __restrict__ sortidx,
                                               float* __restrict__ out) {
    int bp = blockIdx.x;
    int b = bp >> 10;
    int src = sortidx[bp];
    const float4* s = (const float4*)(pooledU + ((size_t)(b << 10) + src) * D_);
    float4* d = (float4*)(out + (size_t)bp * D_);
    d[threadIdx.x] = s[threadIdx.x];
}

// ---------------- deterministic final reduce ----------------
__global__ __launch_bounds__(256) void k_fin(const float* __restrict__ gram_partial,
                                             const float* __restrict__ edge_partial,
                                             const float* __restrict__ ent_partial,
                                             const int* __restrict__ deg,
                                             float* __restrict__ out2) {
    int t = threadIdx.x;
    __shared__ float red[256];
    float t1 = 0.f, t2 = 0.f, t3 = 0.f, ent = 0.f;
    for (int i = t; i < 36 * B_; i += 256) t1 += gram_partial[i];
    for (int i = t; i < B_ * N_; i += 256) t2 += edge_partial[i];
    for (int i = t; i < (B_ * N_) / 8; i += 256) ent += ent_partial[i];
    for (int i = t; i < B_ * N_; i += 256) t3 += (float)deg[i];
    t1 = bsum256(red, t, t1);
    t2 = bsum256(red, t, t2);
    t3 = bsum256(red, t, t3);
    ent = bsum256(red, t, ent);
    if (t == 0) {
        out2[0] = (t1 - 2.f * t2 + t3) / (float)((size_t)B_ * N_ * N_);
        out2[1] = ent / (float)(B_ * N_);
    }
}

extern "C" void kernel_launch(void* const* d_in, const int* in_sizes, int n_in,
                              void* d_out, int out_size, void* d_ws, size_t ws_size,
                              hipStream_t stream) {
    const float* tokens = (const float*)d_in[0];
    const float* tstamp = (const float*)d_in[1];
    const float* W1 = (const float*)d_in[2];
    const float* b1 = (const float*)d_in[3];
    const float* W2 = (const float*)d_in[4];
    const float* b2 = (const float*)d_in[5];
    float* out = (float*)d_out;

    char* wsp = (char*)d_ws;
    size_t off = 0;
    auto alloc = [&](size_t bytes) -> void* {
        void* p = wsp + off;
        off += (bytes + 255) & ~(size_t)255;
        return p;
    };
    // tn fp32 (dead after k_rescore) reused as agg
    float* tn = (float*)alloc(sizeof(float) * (size_t)B_ * N_ * D_);      // 16.8 MB
    float* agg = tn;
    // S bf16 (dead after k_cand16) overlaps assign fp32 (written later)
    ushort* S = (ushort*)alloc(sizeof(float) * (size_t)B_ * N_ * NP_);    // 67.1 MB
    float* assign = (float*)S;
    // tnbf (dead after k_simgemm) reused as tokT
    ushort* tnbf = (ushort*)alloc(sizeof(ushort) * (size_t)B_ * N_ * D_); // 8.4 MB
    ushort* tokT = tnbf;
    float* hbuf = (float*)alloc(sizeof(float) * (size_t)B_ * N_ * H_);    // 8.4 MB
    ushort* assignT = (ushort*)alloc(sizeof(ushort) * (size_t)B_ * NP_ * N_);  // 33.6 MB
    float* pooledU = (float*)alloc(sizeof(float) * (size_t)B_ * NP_ * D_);     // 8.4 MB
    float* pooltU = (float*)alloc(sizeof(float) * (size_t)B_ * NP_);
    int* candbuf = (int*)alloc(sizeof(int) * (size_t)B_ * N_ * 16);
    int* topkbuf = (int*)alloc(sizeof(int) * (size_t)B_ * N_ * K_);
    int* nbrbuf = (int*)alloc(sizeof(int) * (size_t)B_ * N_ * K_);
    int* degbuf = (int*)alloc(sizeof(int) * (size_t)B_ * N_);
    int* sortidx = (int*)alloc(sizeof(int) * (size_t)B_ * NP_);
    float* gram_p = (float*)alloc(sizeof(float) * 36 * B_);
    float* edge_p = (float*)alloc(sizeof(float) * (size_t)B_ * N_);
    float* ent_p = (float*)alloc(sizeof(float) * (size_t)(B_ * N_) / 8);

    k_norm<<<B_ * N_, 256, 0, stream>>>(tokens, tn, tnbf);
    k_simgemm<<<dim3(16, 16, B_), 256, 0, stream>>>(tnbf, S);
    k_cand16<<<(B_ * N_) / 4, 256, 0, stream>>>(S, candbuf);
    k_rescore<<<B_ * N_, 64, 0, stream>>>(tn, candbuf, topkbuf);
    k_adj_agg<<<B_ * N_, 64, 0, stream>>>(tokens, topkbuf, nbrbuf, degbuf, agg);
    k_tokT<<<dim3(N_ / 32, D_ / 32, B_), 256, 0, stream>>>(tokens, tokT);
    k_mlp1<<<(B_ * N_) / 8, 128, 0, stream>>>(tokens, agg, W1, b1, hbuf);
    k_mlp2<<<(B_ * N_) / 8, 256, 0, stream>>>(hbuf, W2, b2, assign, ent_p);
    k_asT<<<dim3(N_ / 32, NP_ / 32, B_), 256, 0, stream>>>(assign, assignT);
    k_poolM<<<dim3(2, 8, B_), 256, 0, stream>>>(assignT, tokT, pooledU);
    k_poolt<<<dim3(NP_ / 256, B_), 256, 0, stream>>>(assign, tstamp, pooltU);
    k_gramM<<<dim3(36, B_), 256, 0, stream>>>(assignT, gram_p);
    k_edge<<<B_ * N_, 64, 0, stream>>>(assign, nbrbuf, degbuf, edge_p);
    k_sort<<<B_, 256, 0, stream>>>(pooltU, out + (size_t)B_ * NP_ * D_, sortidx);
    k_gather<<<B_ * NP_, 64, 0, stream>>>(pooledU, sortidx, out);
    k_fin<<<1, 256, 0, stream>>>(gram_p, edge_p, ent_p, degbuf,
                                 out + (size_t)B_ * NP_ * D_ + (size_t)B_ * NP_);
}